// Round 2
// baseline (145.118 us; speedup 1.0000x reference)
//
#include <hip/hip_runtime.h>
#include <math.h>

// MMD loss. Z = concat(X,Y) [8192 x 256] fp32.
// Round 10: R9 postmortem — FETCH/WRITE are KB, so WRITE=34 KB: there was NO
//   spill (R8/R9 spill theory was a unit misread; that's why unroll-1 and
//   launch_bounds changed nothing). Real bottleneck: 520 blocks = 2.03/CU ->
//   only 2 waves/SIMD resident (no latency hiding, all pipes <21%) plus a
//   1.5x tail (8 CUs run a 3rd block while 248 idle; Occupancy 11.4% avg).
//   Fixes: (a) CHUNK=1 -> 2080 one-tile blocks (8x260 XCD swizzle): 3 blocks/
//   CU resident whole run, tail 1.5x -> 1.12x; (b) bandwidth reduction hoisted
//   to a 1-block k_bw kernel writing c2 to ws (k_gram prologue = 1 scalar
//   load; kernel boundary provides coherence); (c) single-tile blocks reduce
//   one double (class is block-uniform) instead of three.
// Math (R5-R9 verified, absmax 0.0): 1-phase bf16 Gram, sq exact fp32;
//   d2 = sq_i + sq_j - 2 z_i.z_j; bandwidth analytic
//   (sum d2 = 2M*S - 2||sum z||^2); K = t+t^2+t^4+t^8+t^16, t=exp(-d2/(4bw));
//   out = (Sxx + Syy - Sxy_both)/n^2, fp64 accumulation.

#define N_HALF 4096
#define DIM 256
#define M_TOT 8192
#define TILE 128
#define NT 64
#define NT_HALF 32
#define NBLK 2080  // 64*65/2 flat triangle tiles, one per block; 2080 = 8*260

typedef unsigned short ushort_t;
typedef __attribute__((ext_vector_type(8))) short short8;   // 8 bf16 = 4 VGPRs
typedef __attribute__((ext_vector_type(4))) float floatx4;  // MFMA C/D

// Fragment-swizzled bf16 Z (4 MB). For row-block rb (16 rows) and k-chunk kk
// (32 k): g_zf[rb*4096 + kk*512 + m*32 + q*8 + j] = Z[rb*16+m][kk*32+q*8+j].
// MFMA frag load (lane = q*16+m) reads 16 contiguous bytes; wave = 1 KB run.
__device__ ushort_t g_zf[M_TOT * DIM];

__device__ __forceinline__ ushort_t f2bf(float f) {  // RNE, finite inputs
    unsigned u = __float_as_uint(f);
    u += 0x7fffu + ((u >> 16) & 1u);
    return (ushort_t)(u >> 16);
}

__device__ __forceinline__ void load_frags(const ushort_t* aP, const ushort_t* bP,
                                           int kk, short8 (&af)[4], short8 (&bf)[4]) {
#pragma unroll
    for (int mi = 0; mi < 4; ++mi)
        af[mi] = *(const short8*)(aP + (size_t)mi * 4096 + kk * 512);
#pragma unroll
    for (int ni = 0; ni < 4; ++ni)
        bf[ni] = *(const short8*)(bP + (size_t)ni * 4096 + kk * 512);
}

__device__ __forceinline__ void mfma16(const short8 (&af)[4], const short8 (&bf)[4],
                                       floatx4 (&accv)[4][4]) {
#pragma unroll
    for (int mi = 0; mi < 4; ++mi)
#pragma unroll
        for (int ni = 0; ni < 4; ++ni)
            accv[mi][ni] = __builtin_amdgcn_mfma_f32_16x16x32_bf16(
                af[mi], bf[ni], accv[mi][ni], 0, 0, 0);
}

// ---------------- k_prep: convert(swizzled) + row norms + col sums -----------
// 512 blocks x 256 threads; wave w owns 4 rows; lane l owns cols [4l,4l+4).
__global__ __launch_bounds__(256) void k_prep(const float* __restrict__ X,
                                              const float* __restrict__ Y,
                                              float* __restrict__ sq,
                                              float* __restrict__ colsum_r,
                                              float* __restrict__ Ssum_r) {
    __shared__ float cpart[4][256];
    __shared__ float spart[4];
    const int t = threadIdx.x, wave = t >> 6, lane = t & 63;
    const int row0 = blockIdx.x * 16 + wave * 4;
    // swizzle coords for this lane's 4 columns [4l, 4l+4)
    const int kk = lane >> 3, q = (lane >> 1) & 3, j0 = (lane & 1) * 4;
    float c0 = 0.f, c1 = 0.f, c2 = 0.f, c3 = 0.f, ssum = 0.f;
#pragma unroll
    for (int i = 0; i < 4; ++i) {
        const int row = row0 + i;
        const float* p = (row < N_HALF) ? (X + (size_t)row * DIM)
                                        : (Y + (size_t)(row - N_HALF) * DIM);
        const float4 v = *((const float4*)p + lane);
        ushort4 hi;
        hi.x = f2bf(v.x); hi.y = f2bf(v.y); hi.z = f2bf(v.z); hi.w = f2bf(v.w);
        const int rb = row >> 4, m = row & 15;
        *(ushort4*)(g_zf + (size_t)rb * 4096 + kk * 512 + m * 32 + q * 8 + j0) = hi;
        c0 += v.x; c1 += v.y; c2 += v.z; c3 += v.w;
        float s = fmaf(v.x, v.x, fmaf(v.y, v.y, fmaf(v.z, v.z, v.w * v.w)));
#pragma unroll
        for (int off = 32; off > 0; off >>= 1) s += __shfl_xor(s, off);
        if (lane == 0) sq[row] = s;
        ssum += s;  // butterfly left full sum in every lane
    }
    float4 cp; cp.x = c0; cp.y = c1; cp.z = c2; cp.w = c3;
    *(float4*)&cpart[wave][lane * 4] = cp;
    if (lane == 0) spart[wave] = ssum;
    __syncthreads();
    const float cs = cpart[0][t] + cpart[1][t] + cpart[2][t] + cpart[3][t];
    const int rep = blockIdx.x & 7;  // 8 replicas -> 64 adds/address
    atomicAdd(&colsum_r[rep * 256 + t], cs);  // poison -3e-13/rep: harmless
    if (t == 0) atomicAdd(&Ssum_r[rep], spart[0] + spart[1] + spart[2] + spart[3]);
}

// ---------------- k_bw: one block computes exp2 scale c2 once ----------------
// Same summation order as the old per-block prologue -> bit-identical c2.
__global__ __launch_bounds__(256) void k_bw(const float* __restrict__ colsum_r,
                                            const float* __restrict__ Ssum_r,
                                            float* __restrict__ c2out) {
    __shared__ double sred[4];
    const int t = threadIdx.x, lane = t & 63, wave = t >> 6;
    float csf = 0.f;
#pragma unroll
    for (int r = 0; r < 8; ++r) csf += colsum_r[r * 256 + t];
    double p = (double)csf * (double)csf;
#pragma unroll
    for (int off = 32; off > 0; off >>= 1) p += __shfl_xor(p, off);
    if (lane == 0) sred[wave] = p;
    __syncthreads();
    if (t == 0) {
        const double SS = sred[0] + sred[1] + sred[2] + sred[3];
        float Sf = 0.f;
#pragma unroll
        for (int r = 0; r < 8; ++r) Sf += Ssum_r[r];
        const double sum_d2 = 2.0 * (double)M_TOT * (double)Sf - 2.0 * SS;
        const double bw = sum_d2 / ((double)M_TOT * (double)M_TOT - (double)M_TOT);
        c2out[0] = (float)(1.4426950408889634 / (4.0 * bw));  // exp2 scale
    }
}

// ---------------- k_gram: one 128x128 flat-triangle tile per block -----------
// 2080 blocks x 256 threads; ~3 blocks/CU resident, 8.125 sequential per CU.
__global__ __launch_bounds__(256, 2) void k_gram(const float* __restrict__ sq,
                                                 const float* __restrict__ c2p,
                                                 double* __restrict__ acc,
                                                 unsigned* __restrict__ cnt,
                                                 float* __restrict__ out) {
    // XCD-band swizzle (2080 = 8*260): same-XCD blocks contiguous in triangle.
    const int bid = (int)blockIdx.x;
    const int f0 = (bid & 7) * 260 + (bid >> 3);  // flat tile index

    __shared__ double redw[4];

    const int t = threadIdx.x;
    const int lane = t & 63, wave = t >> 6;
    const int l15 = lane & 15, quad = lane >> 4;
    const int wrow = (wave >> 1) * 64, wcol = (wave & 1) * 64;

    const float c2 = c2p[0];  // wave-uniform scalar load
    const float twoc2 = 2.f * c2;

    // triangular decode of f0 -> (ti, tj), tj >= ti
    int ti = (int)((129.0f - sqrtf(16641.0f - 8.0f * (float)f0)) * 0.5f);
    if (ti < 0) ti = 0; if (ti > NT - 1) ti = NT - 1;
    while (ti * NT - ti * (ti - 1) / 2 > f0) --ti;
    while ((ti + 1) * NT - (ti + 1) * ti / 2 <= f0) ++ti;
    const int tj = ti + (f0 - (ti * NT - ti * (ti - 1) / 2));

    const int laneoff = l15 * 32 + quad * 8;
    const ushort_t* aP = g_zf + (size_t)((ti * TILE + wrow) >> 4) * 4096 + laneoff;
    const ushort_t* bP = g_zf + (size_t)((tj * TILE + wcol) >> 4) * 4096 + laneoff;

    short8 af0[4], bf0[4], af1[4], bf1[4];
    load_frags(aP, bP, 0, af0, bf0);  // prime kk=0

    floatx4 accv[4][4];
#pragma unroll
    for (int mi = 0; mi < 4; ++mi)
#pragma unroll
        for (int ni = 0; ni < 4; ++ni) accv[mi][ni] = (floatx4)0.f;

#pragma unroll
    for (int kk = 0; kk < 8; kk += 2) {
        load_frags(aP, bP, kk + 1, af1, bf1);   // in flight over mfma kk
        mfma16(af0, bf0, accv);
        if (kk + 2 < 8) load_frags(aP, bP, kk + 2, af0, bf0);
        mfma16(af1, bf1, accv);
    }

    // ---- epilogue. C/D: col = lane&15, row = quad*4+reg.
    const int arow0 = ti * TILE, brow0 = tj * TILE;
    float nsj[4];
#pragma unroll
    for (int ni = 0; ni < 4; ++ni)
        nsj[ni] = -c2 * sq[brow0 + wcol + ni * 16 + l15];
    floatx4 nsi4[4];
#pragma unroll
    for (int mi = 0; mi < 4; ++mi) {
        const float4 sv = *(const float4*)&sq[arow0 + wrow + mi * 16 + quad * 4];
        nsi4[mi][0] = -c2 * sv.x; nsi4[mi][1] = -c2 * sv.y;
        nsi4[mi][2] = -c2 * sv.z; nsi4[mi][3] = -c2 * sv.w;
    }
    floatx4 sum4 = (floatx4)0.f;
#pragma unroll
    for (int mi = 0; mi < 4; ++mi) {
#pragma unroll
        for (int ni = 0; ni < 4; ++ni) {
            const floatx4 addv = nsi4[mi] + (floatx4)nsj[ni];
            floatx4 arg = twoc2 * accv[mi][ni] + addv;
            floatx4 tt;
#pragma unroll
            for (int r = 0; r < 4; ++r) tt[r] = exp2f(fminf(arg[r], 0.f));
            const floatx4 t2 = tt * tt, t4 = t2 * t2, t8 = t4 * t4, t16 = t8 * t8;
            sum4 += (tt + t2) + (t4 + t8) + t16;
        }
    }
    const float fsum = (sum4[0] + sum4[1]) + (sum4[2] + sum4[3]);
    double contrib = ((ti == tj) ? 1.0 : 2.0) * (double)fsum;

    // ---- block reduction (class is block-uniform: one double) + finalize ----
#pragma unroll
    for (int off = 32; off > 0; off >>= 1) contrib += __shfl_xor(contrib, off);
    if (lane == 0) redw[wave] = contrib;
    __syncthreads();
    if (t == 0) {
        const double s = (redw[0] + redw[1]) + (redw[2] + redw[3]);
        const int cls = (tj < NT_HALF) ? 0 : ((ti < NT_HALF) ? 1 : 2);
        if (s != 0.0) atomicAdd(&acc[cls], s);
        __threadfence();  // release region adds before counter bump
        const unsigned old = atomicAdd(cnt, 1u);
        // counter starts at 0xAAAAAAAA (ws poison) or 0 — accept either
        if (old == (0xAAAAAAAAu + (unsigned)(NBLK - 1)) ||
            old == (unsigned)(NBLK - 1)) {
            const double xx = atomicAdd(&acc[0], 0.0);  // coherent reads
            const double xy = atomicAdd(&acc[1], 0.0);
            const double yy = atomicAdd(&acc[2], 0.0);
            out[0] = (float)((xx + yy - xy) *
                             (1.0 / ((double)N_HALF * (double)N_HALF)));
        }
    }
}

extern "C" void kernel_launch(void* const* d_in, const int* in_sizes, int n_in,
                              void* d_out, int out_size, void* d_ws, size_t ws_size,
                              hipStream_t stream) {
    const float* X = (const float*)d_in[0];
    const float* Y = (const float*)d_in[1];
    char* ws = (char*)d_ws;
    float* sq        = (float*)ws;               // 8192 f32  [0, 32768)
    float* colsum_r  = (float*)(ws + 32768);     // 8*256 f32 [32768, 40960)
    float* Ssum_r    = (float*)(ws + 40960);     // 8 f32     [40960, 40992)
    unsigned* cnt    = (unsigned*)(ws + 40992);  // 1 u32
    double* acc      = (double*)(ws + 41000);    // 3 f64 (8-aligned)
    float* c2ws      = (float*)(ws + 41024);     // 1 f32
    float* out = (float*)d_out;

    hipLaunchKernelGGL(k_prep, dim3(512), dim3(256), 0, stream,
                       X, Y, sq, colsum_r, Ssum_r);
    hipLaunchKernelGGL(k_bw, dim3(1), dim3(256), 0, stream,
                       colsum_r, Ssum_r, c2ws);
    hipLaunchKernelGGL(k_gram, dim3(NBLK), dim3(256), 0, stream,
                       sq, c2ws, acc, cnt, out);
}

// Round 3
// 117.731 us; speedup vs baseline: 1.2326x; 1.2326x over previous
//
#include <hip/hip_runtime.h>
#include <math.h>

// MMD loss. Z = concat(X,Y) [8192 x 256] fp32.
// Round 11: R10 regression (2080 blocks: 75->90us) = per-block overhead x4 +
//   4x finalize atomics (WRITE 34->130KB); occupancy rose but didn't pay.
//   Real bottleneck (R9/R10 counters: all pipes <21% busy): direct-global
//   fragment loads give prefetch depth 1; each kk-batch exposes ~300-900cyc
//   L2/L3 latency vs ~80cyc of MFMA cover, with only 2 waves/SIMD.
//   Fix: m97-style bulk LDS staging. Per kk-step the block issues 16
//   global_load_lds dwordx4 (A 8KB + B 8KB slices, linear copy of g_zf's
//   fragment layout) into 2x16KB double-buffered LDS; stage for step k+1
//   issues BEFORE compute of step k; ONE __syncthreads per step (its vmcnt0
//   drain doubles as buffer-ready + overwrite guard) pays only latency-compute.
//   32KB LDS/block -> 2 blocks/CU (520 blocks, (256,2)) for cross-block cover.
//   Grid reverted to 520xCHUNK=4; k_bw hoist kept.
// Math (R5-R10 verified, absmax 0.0): 1-phase bf16 Gram, sq exact fp32;
//   d2 = sq_i + sq_j - 2 z_i.z_j; bandwidth analytic
//   (sum d2 = 2M*S - 2||sum z||^2); K = t+t^2+t^4+t^8+t^16, t=exp(-d2/(4bw));
//   out = (Sxx + Syy - Sxy_both)/n^2, fp64 accumulation.

#define N_HALF 4096
#define DIM 256
#define M_TOT 8192
#define TILE 128
#define NT 64
#define NT_HALF 32
#define CHUNK 4
#define NCHUNK 520  // 2080 tiles / 4; 520 = 8 * 65

typedef unsigned short ushort_t;
typedef __attribute__((ext_vector_type(8))) short short8;   // 8 bf16 = 4 VGPRs
typedef __attribute__((ext_vector_type(4))) float floatx4;  // MFMA C/D

// Fragment-swizzled bf16 Z (4 MB). For row-block rb (16 rows) and k-chunk kk
// (32 k): g_zf[rb*4096 + kk*512 + m*32 + q*8 + j] = Z[rb*16+m][kk*32+q*8+j].
// A (rb,kk) chunk is 1 KB contiguous -> gload_lds linear copy; MFMA frag read
// (lane = q*16+m) is 64 distinct contiguous 16B chunks = conflict-free b128.
__device__ ushort_t g_zf[M_TOT * DIM];

__device__ __forceinline__ ushort_t f2bf(float f) {  // RNE, finite inputs
    unsigned u = __float_as_uint(f);
    u += 0x7fffu + ((u >> 16) & 1u);
    return (ushort_t)(u >> 16);
}

__device__ __forceinline__ void gload_lds16(const ushort_t* g, ushort_t* l) {
    __builtin_amdgcn_global_load_lds(
        (const __attribute__((address_space(1))) void*)g,
        (__attribute__((address_space(3))) void*)l, 16, 0, 0);
}

// Stage one kk-slice (A 8KB + B 8KB = 16 chunks of 1KB) into LDS.
// Wave w stages chunks {2w, 2w+1} of A and of B: 4 insts/wave, 1KB each
// (lane gaddr = chunk + lane*16B; LDS dest = uniform base + lane*16B).
__device__ __forceinline__ void stage_slice(const ushort_t* gA, const ushort_t* gB,
                                            ushort_t* lA, ushort_t* lB,
                                            int wave, int lane) {
#pragma unroll
    for (int i = 0; i < 2; ++i) {
        const int c = wave * 2 + i;
        gload_lds16(gA + (size_t)c * 4096 + lane * 8, lA + c * 512);
        gload_lds16(gB + (size_t)c * 4096 + lane * 8, lB + c * 512);
    }
}

__device__ __forceinline__ void compute_kk(const ushort_t* lA, const ushort_t* lB,
                                           int a0, int b0, int laneoff,
                                           floatx4 (&accv)[4][4]) {
    short8 af[4], bf[4];
#pragma unroll
    for (int mi = 0; mi < 4; ++mi)
        af[mi] = *(const short8*)(lA + (a0 + mi) * 512 + laneoff);
#pragma unroll
    for (int ni = 0; ni < 4; ++ni)
        bf[ni] = *(const short8*)(lB + (b0 + ni) * 512 + laneoff);
#pragma unroll
    for (int mi = 0; mi < 4; ++mi)
#pragma unroll
        for (int ni = 0; ni < 4; ++ni)
            accv[mi][ni] = __builtin_amdgcn_mfma_f32_16x16x32_bf16(
                af[mi], bf[ni], accv[mi][ni], 0, 0, 0);
}

// ---------------- k_prep: convert(swizzled) + row norms + col sums -----------
// 512 blocks x 256 threads; wave w owns 4 rows; lane l owns cols [4l,4l+4).
__global__ __launch_bounds__(256) void k_prep(const float* __restrict__ X,
                                              const float* __restrict__ Y,
                                              float* __restrict__ sq,
                                              float* __restrict__ colsum_r,
                                              float* __restrict__ Ssum_r) {
    __shared__ float cpart[4][256];
    __shared__ float spart[4];
    const int t = threadIdx.x, wave = t >> 6, lane = t & 63;
    const int row0 = blockIdx.x * 16 + wave * 4;
    // swizzle coords for this lane's 4 columns [4l, 4l+4)
    const int kk = lane >> 3, q = (lane >> 1) & 3, j0 = (lane & 1) * 4;
    float c0 = 0.f, c1 = 0.f, c2 = 0.f, c3 = 0.f, ssum = 0.f;
#pragma unroll
    for (int i = 0; i < 4; ++i) {
        const int row = row0 + i;
        const float* p = (row < N_HALF) ? (X + (size_t)row * DIM)
                                        : (Y + (size_t)(row - N_HALF) * DIM);
        const float4 v = *((const float4*)p + lane);
        ushort4 hi;
        hi.x = f2bf(v.x); hi.y = f2bf(v.y); hi.z = f2bf(v.z); hi.w = f2bf(v.w);
        const int rb = row >> 4, m = row & 15;
        *(ushort4*)(g_zf + (size_t)rb * 4096 + kk * 512 + m * 32 + q * 8 + j0) = hi;
        c0 += v.x; c1 += v.y; c2 += v.z; c3 += v.w;
        float s = fmaf(v.x, v.x, fmaf(v.y, v.y, fmaf(v.z, v.z, v.w * v.w)));
#pragma unroll
        for (int off = 32; off > 0; off >>= 1) s += __shfl_xor(s, off);
        if (lane == 0) sq[row] = s;
        ssum += s;  // butterfly left full sum in every lane
    }
    float4 cp; cp.x = c0; cp.y = c1; cp.z = c2; cp.w = c3;
    *(float4*)&cpart[wave][lane * 4] = cp;
    if (lane == 0) spart[wave] = ssum;
    __syncthreads();
    const float cs = cpart[0][t] + cpart[1][t] + cpart[2][t] + cpart[3][t];
    const int rep = blockIdx.x & 7;  // 8 replicas -> 64 adds/address
    atomicAdd(&colsum_r[rep * 256 + t], cs);  // poison -3e-13/rep: harmless
    if (t == 0) atomicAdd(&Ssum_r[rep], spart[0] + spart[1] + spart[2] + spart[3]);
}

// ---------------- k_bw: one block computes exp2 scale c2 once ----------------
// Same summation order as the old per-block prologue -> bit-identical c2.
__global__ __launch_bounds__(256) void k_bw(const float* __restrict__ colsum_r,
                                            const float* __restrict__ Ssum_r,
                                            float* __restrict__ c2out) {
    __shared__ double sred[4];
    const int t = threadIdx.x, lane = t & 63, wave = t >> 6;
    float csf = 0.f;
#pragma unroll
    for (int r = 0; r < 8; ++r) csf += colsum_r[r * 256 + t];
    double p = (double)csf * (double)csf;
#pragma unroll
    for (int off = 32; off > 0; off >>= 1) p += __shfl_xor(p, off);
    if (lane == 0) sred[wave] = p;
    __syncthreads();
    if (t == 0) {
        const double SS = sred[0] + sred[1] + sred[2] + sred[3];
        float Sf = 0.f;
#pragma unroll
        for (int r = 0; r < 8; ++r) Sf += Ssum_r[r];
        const double sum_d2 = 2.0 * (double)M_TOT * (double)Sf - 2.0 * SS;
        const double bw = sum_d2 / ((double)M_TOT * (double)M_TOT - (double)M_TOT);
        c2out[0] = (float)(1.4426950408889634 / (4.0 * bw));  // exp2 scale
    }
}

// ---------------- k_gram: LDS-staged pipelined MFMA Gram ---------------------
// 520 blocks x 256 threads; 4 consecutive flat-triangle tiles per block;
// 32 KB LDS double buffer -> 2 blocks/CU.
__global__ __launch_bounds__(256, 2) void k_gram(const float* __restrict__ sq,
                                                 const float* __restrict__ c2p,
                                                 double* __restrict__ acc,
                                                 unsigned* __restrict__ cnt,
                                                 float* __restrict__ out) {
    // buf: A slice [0,4096), B slice [4096,8192) ushorts (8 KB each).
    __shared__ __attribute__((aligned(16))) ushort_t lds[2][8192];
    __shared__ double redw[4][3];

    // XCD-band swizzle (520 = 8*65): same-XCD blocks contiguous in triangle.
    const int bid = (int)blockIdx.x;
    const int cc = (bid & 7) * 65 + (bid >> 3);
    const int f0 = cc * CHUNK;  // first flat tile index of this block

    const int t = threadIdx.x;
    const int lane = t & 63, wave = t >> 6;
    const int l15 = lane & 15, quad = lane >> 4;
    const int wrow = (wave >> 1) * 64, wcol = (wave & 1) * 64;
    const int a0 = (wave >> 1) * 4, b0 = (wave & 1) * 4;  // frag chunk bases
    const int laneoff = l15 * 32 + quad * 8;              // within 1KB chunk

    const float c2 = c2p[0];  // wave-uniform scalar load
    const float twoc2 = 2.f * c2;

    // triangular decode of f0 -> (ti, tj), tj >= ti
    int ti = (int)((129.0f - sqrtf(16641.0f - 8.0f * (float)f0)) * 0.5f);
    if (ti < 0) ti = 0; if (ti > NT - 1) ti = NT - 1;
    while (ti * NT - ti * (ti - 1) / 2 > f0) --ti;
    while ((ti + 1) * NT - (ti + 1) * ti / 2 <= f0) ++ti;
    int tj = ti + (f0 - (ti * NT - ti * (ti - 1) / 2));

    const ushort_t* cgA = g_zf + (size_t)ti * 8 * 4096;
    const ushort_t* cgB = g_zf + (size_t)tj * 8 * 4096;

    stage_slice(cgA, cgB, lds[0], lds[0] + 4096, wave, lane);  // prime kk=0
    __syncthreads();  // drain: buf0 ready

    double lxx = 0.0, lxy = 0.0, lyy = 0.0;
    int cur = 0;

#pragma unroll 1
    for (int s = 0; s < CHUNK; ++s) {
        int nti = ti, ntj = tj + 1;
        if (ntj == NT) { ++nti; ntj = nti; }
        const ushort_t* ngA = g_zf + (size_t)nti * 8 * 4096;
        const ushort_t* ngB = g_zf + (size_t)ntj * 8 * 4096;

        floatx4 accv[4][4];
#pragma unroll
        for (int mi = 0; mi < 4; ++mi)
#pragma unroll
            for (int ni = 0; ni < 4; ++ni) accv[mi][ni] = (floatx4)0.f;

#pragma unroll
        for (int kk = 0; kk < 8; ++kk) {
            // stage NEXT slice into the other buffer, then compute current;
            // trailing __syncthreads drains the stage (residual ~= lat-compute)
            // AND guards the swap. Stage target's readers finished before the
            // previous barrier.
            if (kk < 7)
                stage_slice(cgA + (kk + 1) * 512, cgB + (kk + 1) * 512,
                            lds[cur ^ 1], lds[cur ^ 1] + 4096, wave, lane);
            else if (s < CHUNK - 1)
                stage_slice(ngA, ngB,
                            lds[cur ^ 1], lds[cur ^ 1] + 4096, wave, lane);
            compute_kk(lds[cur], lds[cur] + 4096, a0, b0, laneoff, accv);
            __syncthreads();
            cur ^= 1;
        }

        // ---- epilogue for (ti, tj). C/D: col = lane&15, row = quad*4+reg.
        // (next tile's kk=0 already resident in lds[cur]; no LDS use here)
        const int arow0 = ti * TILE, brow0 = tj * TILE;
        float nsj[4];
#pragma unroll
        for (int ni = 0; ni < 4; ++ni)
            nsj[ni] = -c2 * sq[brow0 + wcol + ni * 16 + l15];
        floatx4 nsi4[4];
#pragma unroll
        for (int mi = 0; mi < 4; ++mi) {
            const float4 sv = *(const float4*)&sq[arow0 + wrow + mi * 16 + quad * 4];
            nsi4[mi][0] = -c2 * sv.x; nsi4[mi][1] = -c2 * sv.y;
            nsi4[mi][2] = -c2 * sv.z; nsi4[mi][3] = -c2 * sv.w;
        }
        floatx4 sum4 = (floatx4)0.f;
#pragma unroll
        for (int mi = 0; mi < 4; ++mi) {
#pragma unroll
            for (int ni = 0; ni < 4; ++ni) {
                const floatx4 addv = nsi4[mi] + (floatx4)nsj[ni];
                floatx4 arg = twoc2 * accv[mi][ni] + addv;
                floatx4 tt;
#pragma unroll
                for (int r = 0; r < 4; ++r) tt[r] = exp2f(fminf(arg[r], 0.f));
                const floatx4 t2 = tt * tt, t4 = t2 * t2, t8 = t4 * t4, t16 = t8 * t8;
                sum4 += (tt + t2) + (t4 + t8) + t16;
            }
        }
        const float fsum = (sum4[0] + sum4[1]) + (sum4[2] + sum4[3]);
        const double contrib = ((ti == tj) ? 1.0 : 2.0) * (double)fsum;
        if (tj < NT_HALF)       lxx += contrib;   // block-uniform branches
        else if (ti < NT_HALF)  lxy += contrib;
        else                    lyy += contrib;

        ti = nti; tj = ntj; cgA = ngA; cgB = ngB;
    }

    // ---- block reduction + finalize ----
#pragma unroll
    for (int off = 32; off > 0; off >>= 1) {
        lxx += __shfl_xor(lxx, off);
        lxy += __shfl_xor(lxy, off);
        lyy += __shfl_xor(lyy, off);
    }
    if (lane == 0) { redw[wave][0] = lxx; redw[wave][1] = lxy; redw[wave][2] = lyy; }
    __syncthreads();
    if (t == 0) {
        double sxx = 0.0, sxy = 0.0, syy = 0.0;
#pragma unroll
        for (int wv = 0; wv < 4; ++wv) {
            sxx += redw[wv][0]; sxy += redw[wv][1]; syy += redw[wv][2];
        }
        if (sxx != 0.0) atomicAdd(&acc[0], sxx);
        if (sxy != 0.0) atomicAdd(&acc[1], sxy);
        if (syy != 0.0) atomicAdd(&acc[2], syy);
        __threadfence();  // release region adds before counter bump
        const unsigned old = atomicAdd(cnt, 1u);
        // counter starts at 0xAAAAAAAA (ws poison) or 0 — accept either
        if (old == (0xAAAAAAAAu + (unsigned)(NCHUNK - 1)) ||
            old == (unsigned)(NCHUNK - 1)) {
            const double xx = atomicAdd(&acc[0], 0.0);  // coherent reads
            const double xy = atomicAdd(&acc[1], 0.0);
            const double yy = atomicAdd(&acc[2], 0.0);
            out[0] = (float)((xx + yy - xy) *
                             (1.0 / ((double)N_HALF * (double)N_HALF)));
        }
    }
}

extern "C" void kernel_launch(void* const* d_in, const int* in_sizes, int n_in,
                              void* d_out, int out_size, void* d_ws, size_t ws_size,
                              hipStream_t stream) {
    const float* X = (const float*)d_in[0];
    const float* Y = (const float*)d_in[1];
    char* ws = (char*)d_ws;
    float* sq        = (float*)ws;               // 8192 f32  [0, 32768)
    float* colsum_r  = (float*)(ws + 32768);     // 8*256 f32 [32768, 40960)
    float* Ssum_r    = (float*)(ws + 40960);     // 8 f32     [40960, 40992)
    unsigned* cnt    = (unsigned*)(ws + 40992);  // 1 u32
    double* acc      = (double*)(ws + 41000);    // 3 f64 (8-aligned)
    float* c2ws      = (float*)(ws + 41024);     // 1 f32
    float* out = (float*)d_out;

    hipLaunchKernelGGL(k_prep, dim3(512), dim3(256), 0, stream,
                       X, Y, sq, colsum_r, Ssum_r);
    hipLaunchKernelGGL(k_bw, dim3(1), dim3(256), 0, stream,
                       colsum_r, Ssum_r, c2ws);
    hipLaunchKernelGGL(k_gram, dim3(NCHUNK), dim3(256), 0, stream,
                       sq, c2ws, acc, cnt, out);
}

// Round 4
// 115.534 us; speedup vs baseline: 1.2561x; 1.0190x over previous
//
#include <hip/hip_runtime.h>
#include <math.h>

// MMD loss. Z = concat(X,Y) [8192 x 256] fp32.
// Round 12: R11 counters: SQ_LDS_BANK_CONFLICT = 2.13M = exactly 4 extra
//   cyc per ds_read_b128 (8-way: old chunk layout m*32+q*8 put 8 lanes on one
//   4-bank group). Fixes:
//   (a) g_zf chunk layout m*32+q*8 -> q*128+m*8: frag read addr becomes
//       lane*16B linear -> conflict-free; staging stays a linear copy
//       (both sides linear, no swizzle needed). Bit-identical values.
//   (b) stage 2 kk-slices per LDS buffer (32KB buf, 64KB total): 16 barriers
//       per block instead of 32, each covering ~700cyc compute vs ~300 lat.
//   (c) grid 520 -> 512 (2.0 blocks/CU exact; 8x64 XCD-clean); 32 blocks
//       (cc%16==0, 4 per XCD) take a 5th tile: tail 1.5x -> 1.125x.
// Math (R5-R11 verified, absmax 0.0): 1-phase bf16 Gram, sq exact fp32;
//   d2 = sq_i + sq_j - 2 z_i.z_j; bandwidth analytic
//   (sum d2 = 2M*S - 2||sum z||^2); K = t+t^2+t^4+t^8+t^16, t=exp(-d2/(4bw));
//   out = (Sxx + Syy - Sxy_both)/n^2, fp64 accumulation.

#define N_HALF 4096
#define DIM 256
#define M_TOT 8192
#define TILE 128
#define NT 64
#define NT_HALF 32
#define NCHUNK 512  // blocks; 480 do 4 tiles, 32 (cc%16==0) do 5: 2080 total

typedef unsigned short ushort_t;
typedef __attribute__((ext_vector_type(8))) short short8;   // 8 bf16 = 4 VGPRs
typedef __attribute__((ext_vector_type(4))) float floatx4;  // MFMA C/D

// Fragment-swizzled bf16 Z (4 MB). For row-block rb (16 rows) and k-chunk kk
// (32 k): g_zf[rb*4096 + kk*512 + q*128 + m*8 + j] = Z[rb*16+m][kk*32+q*8+j].
// The 16B unit of lane (quad=q, l15=m) sits at byte lane*16 within the 1KB
// chunk: MFMA frag ds_read_b128 is linear in lane -> conflict-free; staging
// global_load_lds (dest base+lane*16, src +lane*16) is a pure linear copy.
__device__ ushort_t g_zf[M_TOT * DIM];

__device__ __forceinline__ ushort_t f2bf(float f) {  // RNE, finite inputs
    unsigned u = __float_as_uint(f);
    u += 0x7fffu + ((u >> 16) & 1u);
    return (ushort_t)(u >> 16);
}

__device__ __forceinline__ void gload_lds16(const ushort_t* g, ushort_t* l) {
    __builtin_amdgcn_global_load_lds(
        (const __attribute__((address_space(1))) void*)g,
        (__attribute__((address_space(3))) void*)l, 16, 0, 0);
}

// Stage two consecutive kk-slices (A 16KB + B 16KB) into one LDS buffer.
// Buffer layout (ushorts): A slice s chunk c at s*4096 + c*512;
//                          B slice s chunk c at 8192 + s*4096 + c*512.
// Wave w stages chunks {2w, 2w+1}: 8 gload_lds of 1KB per wave.
__device__ __forceinline__ void stage_slice2(const ushort_t* gA, const ushort_t* gB,
                                             ushort_t* buf, int kk0,
                                             int wave, int lane) {
#pragma unroll
    for (int s = 0; s < 2; ++s) {
#pragma unroll
        for (int i = 0; i < 2; ++i) {
            const int c = wave * 2 + i;
            gload_lds16(gA + (size_t)c * 4096 + (kk0 + s) * 512 + lane * 8,
                        buf + s * 4096 + c * 512);
            gload_lds16(gB + (size_t)c * 4096 + (kk0 + s) * 512 + lane * 8,
                        buf + 8192 + s * 4096 + c * 512);
        }
    }
}

__device__ __forceinline__ void compute_kk(const ushort_t* lA, const ushort_t* lB,
                                           int a0, int b0, int laneoff,
                                           floatx4 (&accv)[4][4]) {
    short8 af[4], bf[4];
#pragma unroll
    for (int mi = 0; mi < 4; ++mi)
        af[mi] = *(const short8*)(lA + (a0 + mi) * 512 + laneoff);
#pragma unroll
    for (int ni = 0; ni < 4; ++ni)
        bf[ni] = *(const short8*)(lB + (b0 + ni) * 512 + laneoff);
#pragma unroll
    for (int mi = 0; mi < 4; ++mi)
#pragma unroll
        for (int ni = 0; ni < 4; ++ni)
            accv[mi][ni] = __builtin_amdgcn_mfma_f32_16x16x32_bf16(
                af[mi], bf[ni], accv[mi][ni], 0, 0, 0);
}

// ---------------- k_prep: convert(swizzled) + row norms + col sums -----------
// 512 blocks x 256 threads; wave w owns 4 rows; lane l owns cols [4l,4l+4).
__global__ __launch_bounds__(256) void k_prep(const float* __restrict__ X,
                                              const float* __restrict__ Y,
                                              float* __restrict__ sq,
                                              float* __restrict__ colsum_r,
                                              float* __restrict__ Ssum_r) {
    __shared__ float cpart[4][256];
    __shared__ float spart[4];
    const int t = threadIdx.x, wave = t >> 6, lane = t & 63;
    const int row0 = blockIdx.x * 16 + wave * 4;
    // swizzle coords for this lane's 4 columns [4l, 4l+4)
    const int kk = lane >> 3, q = (lane >> 1) & 3, j0 = (lane & 1) * 4;
    float c0 = 0.f, c1 = 0.f, c2 = 0.f, c3 = 0.f, ssum = 0.f;
#pragma unroll
    for (int i = 0; i < 4; ++i) {
        const int row = row0 + i;
        const float* p = (row < N_HALF) ? (X + (size_t)row * DIM)
                                        : (Y + (size_t)(row - N_HALF) * DIM);
        const float4 v = *((const float4*)p + lane);
        ushort4 hi;
        hi.x = f2bf(v.x); hi.y = f2bf(v.y); hi.z = f2bf(v.z); hi.w = f2bf(v.w);
        const int rb = row >> 4, m = row & 15;
        *(ushort4*)(g_zf + (size_t)rb * 4096 + kk * 512 + q * 128 + m * 8 + j0) = hi;
        c0 += v.x; c1 += v.y; c2 += v.z; c3 += v.w;
        float s = fmaf(v.x, v.x, fmaf(v.y, v.y, fmaf(v.z, v.z, v.w * v.w)));
#pragma unroll
        for (int off = 32; off > 0; off >>= 1) s += __shfl_xor(s, off);
        if (lane == 0) sq[row] = s;
        ssum += s;  // butterfly left full sum in every lane
    }
    float4 cp; cp.x = c0; cp.y = c1; cp.z = c2; cp.w = c3;
    *(float4*)&cpart[wave][lane * 4] = cp;
    if (lane == 0) spart[wave] = ssum;
    __syncthreads();
    const float cs = cpart[0][t] + cpart[1][t] + cpart[2][t] + cpart[3][t];
    const int rep = blockIdx.x & 7;  // 8 replicas -> 64 adds/address
    atomicAdd(&colsum_r[rep * 256 + t], cs);  // poison -3e-13/rep: harmless
    if (t == 0) atomicAdd(&Ssum_r[rep], spart[0] + spart[1] + spart[2] + spart[3]);
}

// ---------------- k_bw: one block computes exp2 scale c2 once ----------------
// Same summation order as the old per-block prologue -> bit-identical c2.
__global__ __launch_bounds__(256) void k_bw(const float* __restrict__ colsum_r,
                                            const float* __restrict__ Ssum_r,
                                            float* __restrict__ c2out) {
    __shared__ double sred[4];
    const int t = threadIdx.x, lane = t & 63, wave = t >> 6;
    float csf = 0.f;
#pragma unroll
    for (int r = 0; r < 8; ++r) csf += colsum_r[r * 256 + t];
    double p = (double)csf * (double)csf;
#pragma unroll
    for (int off = 32; off > 0; off >>= 1) p += __shfl_xor(p, off);
    if (lane == 0) sred[wave] = p;
    __syncthreads();
    if (t == 0) {
        const double SS = sred[0] + sred[1] + sred[2] + sred[3];
        float Sf = 0.f;
#pragma unroll
        for (int r = 0; r < 8; ++r) Sf += Ssum_r[r];
        const double sum_d2 = 2.0 * (double)M_TOT * (double)Sf - 2.0 * SS;
        const double bw = sum_d2 / ((double)M_TOT * (double)M_TOT - (double)M_TOT);
        c2out[0] = (float)(1.4426950408889634 / (4.0 * bw));  // exp2 scale
    }
}

// ---------------- k_gram: LDS-staged pipelined MFMA Gram ---------------------
// 512 blocks x 256 threads = 2.0 blocks/CU; 64 KB LDS double buffer
// (2 kk-slices per buffer -> 16 barriers/block). 32 blocks take a 5th tile.
__global__ __launch_bounds__(256, 2) void k_gram(const float* __restrict__ sq,
                                                 const float* __restrict__ c2p,
                                                 double* __restrict__ acc,
                                                 unsigned* __restrict__ cnt,
                                                 float* __restrict__ out) {
    // buf: A slices [0,8192), B slices [8192,16384) ushorts (16 KB each).
    __shared__ __attribute__((aligned(16))) ushort_t lds[2][16384];
    __shared__ double redw[4][3];

    // XCD-band swizzle (512 = 8*64): same-XCD blocks contiguous in triangle.
    const int bid = (int)blockIdx.x;
    const int cc = (bid & 7) * 64 + (bid >> 3);
    // 32 long blocks (cc%16==0 -> 4 per XCD) do 5 tiles; rest do 4.
    const int nst = ((cc & 15) == 0) ? 5 : 4;
    const int f0 = cc * 4 + ((cc + 15) >> 4);  // first flat tile of this block

    const int t = threadIdx.x;
    const int lane = t & 63, wave = t >> 6;
    const int l15 = lane & 15, quad = lane >> 4;
    const int wrow = (wave >> 1) * 64, wcol = (wave & 1) * 64;
    const int a0 = (wave >> 1) * 4, b0 = (wave & 1) * 4;  // frag chunk bases
    const int laneoff = quad * 128 + l15 * 8;  // = lane*16B: linear, no conflict

    const float c2 = c2p[0];  // wave-uniform scalar load
    const float twoc2 = 2.f * c2;

    // triangular decode of f0 -> (ti, tj), tj >= ti
    int ti = (int)((129.0f - sqrtf(16641.0f - 8.0f * (float)f0)) * 0.5f);
    if (ti < 0) ti = 0; if (ti > NT - 1) ti = NT - 1;
    while (ti * NT - ti * (ti - 1) / 2 > f0) --ti;
    while ((ti + 1) * NT - (ti + 1) * ti / 2 <= f0) ++ti;
    int tj = ti + (f0 - (ti * NT - ti * (ti - 1) / 2));

    const ushort_t* cgA = g_zf + (size_t)ti * 8 * 4096;
    const ushort_t* cgB = g_zf + (size_t)tj * 8 * 4096;

    stage_slice2(cgA, cgB, lds[0], 0, wave, lane);  // prime kk={0,1}
    __syncthreads();  // drain: buf0 ready

    double lxx = 0.0, lxy = 0.0, lyy = 0.0;
    int cur = 0;

#pragma unroll 1
    for (int s = 0; s < nst; ++s) {
        int nti = ti, ntj = tj + 1;
        if (ntj == NT) { ++nti; ntj = nti; }
        const ushort_t* ngA = g_zf + (size_t)nti * 8 * 4096;
        const ushort_t* ngB = g_zf + (size_t)ntj * 8 * 4096;

        floatx4 accv[4][4];
#pragma unroll
        for (int mi = 0; mi < 4; ++mi)
#pragma unroll
            for (int ni = 0; ni < 4; ++ni) accv[mi][ni] = (floatx4)0.f;

#pragma unroll
        for (int kk2 = 0; kk2 < 4; ++kk2) {
            // stage NEXT double-slice into the other buffer, then compute both
            // current slices; trailing __syncthreads drains the stage
            // (residual ~= latency - ~700cyc compute) AND guards the swap.
            if (kk2 < 3)
                stage_slice2(cgA, cgB, lds[cur ^ 1], (kk2 + 1) * 2, wave, lane);
            else if (s < nst - 1)
                stage_slice2(ngA, ngB, lds[cur ^ 1], 0, wave, lane);
            compute_kk(lds[cur], lds[cur] + 8192, a0, b0, laneoff, accv);
            compute_kk(lds[cur] + 4096, lds[cur] + 8192 + 4096,
                       a0, b0, laneoff, accv);
            __syncthreads();
            cur ^= 1;
        }

        // ---- epilogue for (ti, tj). C/D: col = lane&15, row = quad*4+reg.
        // (next tile's kk={0,1} already resident in lds[cur]; no LDS use here)
        const int arow0 = ti * TILE, brow0 = tj * TILE;
        float nsj[4];
#pragma unroll
        for (int ni = 0; ni < 4; ++ni)
            nsj[ni] = -c2 * sq[brow0 + wcol + ni * 16 + l15];
        floatx4 nsi4[4];
#pragma unroll
        for (int mi = 0; mi < 4; ++mi) {
            const float4 sv = *(const float4*)&sq[arow0 + wrow + mi * 16 + quad * 4];
            nsi4[mi][0] = -c2 * sv.x; nsi4[mi][1] = -c2 * sv.y;
            nsi4[mi][2] = -c2 * sv.z; nsi4[mi][3] = -c2 * sv.w;
        }
        floatx4 sum4 = (floatx4)0.f;
#pragma unroll
        for (int mi = 0; mi < 4; ++mi) {
#pragma unroll
            for (int ni = 0; ni < 4; ++ni) {
                const floatx4 addv = nsi4[mi] + (floatx4)nsj[ni];
                floatx4 arg = twoc2 * accv[mi][ni] + addv;
                floatx4 tt;
#pragma unroll
                for (int r = 0; r < 4; ++r) tt[r] = exp2f(fminf(arg[r], 0.f));
                const floatx4 t2 = tt * tt, t4 = t2 * t2, t8 = t4 * t4, t16 = t8 * t8;
                sum4 += (tt + t2) + (t4 + t8) + t16;
            }
        }
        const float fsum = (sum4[0] + sum4[1]) + (sum4[2] + sum4[3]);
        const double contrib = ((ti == tj) ? 1.0 : 2.0) * (double)fsum;
        if (tj < NT_HALF)       lxx += contrib;   // block-uniform branches
        else if (ti < NT_HALF)  lxy += contrib;
        else                    lyy += contrib;

        ti = nti; tj = ntj; cgA = ngA; cgB = ngB;
    }

    // ---- block reduction + finalize ----
#pragma unroll
    for (int off = 32; off > 0; off >>= 1) {
        lxx += __shfl_xor(lxx, off);
        lxy += __shfl_xor(lxy, off);
        lyy += __shfl_xor(lyy, off);
    }
    if (lane == 0) { redw[wave][0] = lxx; redw[wave][1] = lxy; redw[wave][2] = lyy; }
    __syncthreads();
    if (t == 0) {
        double sxx = 0.0, sxy = 0.0, syy = 0.0;
#pragma unroll
        for (int wv = 0; wv < 4; ++wv) {
            sxx += redw[wv][0]; sxy += redw[wv][1]; syy += redw[wv][2];
        }
        if (sxx != 0.0) atomicAdd(&acc[0], sxx);
        if (sxy != 0.0) atomicAdd(&acc[1], sxy);
        if (syy != 0.0) atomicAdd(&acc[2], syy);
        __threadfence();  // release region adds before counter bump
        const unsigned old = atomicAdd(cnt, 1u);
        // counter starts at 0xAAAAAAAA (ws poison) or 0 — accept either
        if (old == (0xAAAAAAAAu + (unsigned)(NCHUNK - 1)) ||
            old == (unsigned)(NCHUNK - 1)) {
            const double xx = atomicAdd(&acc[0], 0.0);  // coherent reads
            const double xy = atomicAdd(&acc[1], 0.0);
            const double yy = atomicAdd(&acc[2], 0.0);
            out[0] = (float)((xx + yy - xy) *
                             (1.0 / ((double)N_HALF * (double)N_HALF)));
        }
    }
}

extern "C" void kernel_launch(void* const* d_in, const int* in_sizes, int n_in,
                              void* d_out, int out_size, void* d_ws, size_t ws_size,
                              hipStream_t stream) {
    const float* X = (const float*)d_in[0];
    const float* Y = (const float*)d_in[1];
    char* ws = (char*)d_ws;
    float* sq        = (float*)ws;               // 8192 f32  [0, 32768)
    float* colsum_r  = (float*)(ws + 32768);     // 8*256 f32 [32768, 40960)
    float* Ssum_r    = (float*)(ws + 40960);     // 8 f32     [40960, 40992)
    unsigned* cnt    = (unsigned*)(ws + 40992);  // 1 u32
    double* acc      = (double*)(ws + 41000);    // 3 f64 (8-aligned)
    float* c2ws      = (float*)(ws + 41024);     // 1 f32
    float* out = (float*)d_out;

    hipLaunchKernelGGL(k_prep, dim3(512), dim3(256), 0, stream,
                       X, Y, sq, colsum_r, Ssum_r);
    hipLaunchKernelGGL(k_bw, dim3(1), dim3(256), 0, stream,
                       colsum_r, Ssum_r, c2ws);
    hipLaunchKernelGGL(k_gram, dim3(NCHUNK), dim3(256), 0, stream,
                       sq, c2ws, acc, cnt, out);
}

// Round 5
// 113.823 us; speedup vs baseline: 1.2749x; 1.0150x over previous
//
#include <hip/hip_runtime.h>
#include <math.h>

// MMD loss. Z = concat(X,Y) [8192 x 256] fp32.
// Round 13: R12 removed conflicts + halved barriers -> only -2.3us. Issue-work
//   model says ~6-8us possible; wall is ~110K cyc/CU. Remaining structural
//   stall: every __syncthreads drains vmcnt(0), so each phase pays full
//   load-return latency (L3 + 512-block burst congestion) with only 2
//   waves/SIMD of cover. Fix = T3+T4 counted-vmcnt ring: 4x16KB LDS buffers,
//   stage stream 3 slices ahead, per phase [s_waitcnt vmcnt(8); raw s_barrier;
//   ds_read frags; issue stage(g+3); setprio(1) MFMA setprio(0)]. Loads stay
//   in flight ACROSS barriers (never drain to 0 in steady state); tail of last
//   tile uses vmcnt(4)/vmcnt(0). vmcnt in-order retire => "<=8 outstanding"
//   proves slice-g complete even with epilogue sq loads in the queue.
//   k_prep/k_bw byte-identical to R12 (isolate the k_gram effect).
// Math (R5-R12 verified, absmax 0.0): 1-phase bf16 Gram, sq exact fp32;
//   d2 = sq_i + sq_j - 2 z_i.z_j; bandwidth analytic
//   (sum d2 = 2M*S - 2||sum z||^2); K = t+t^2+t^4+t^8+t^16, t=exp(-d2/(4bw));
//   out = (Sxx + Syy - Sxy_both)/n^2, fp64 accumulation.

#define N_HALF 4096
#define DIM 256
#define M_TOT 8192
#define TILE 128
#define NT 64
#define NT_HALF 32
#define NCHUNK 512  // blocks; 480 do 4 tiles, 32 (cc%16==0) do 5: 2080 total

typedef unsigned short ushort_t;
typedef __attribute__((ext_vector_type(8))) short short8;   // 8 bf16 = 4 VGPRs
typedef __attribute__((ext_vector_type(4))) float floatx4;  // MFMA C/D

// Fragment-swizzled bf16 Z (4 MB). For row-block rb (16 rows) and k-chunk kk
// (32 k): g_zf[rb*4096 + kk*512 + q*128 + m*8 + j] = Z[rb*16+m][kk*32+q*8+j].
// The 16B unit of lane (quad=q, l15=m) sits at byte lane*16 within the 1KB
// chunk: MFMA frag ds_read_b128 is linear in lane -> conflict-free; staging
// global_load_lds (dest base+lane*16, src +lane*16) is a pure linear copy.
__device__ ushort_t g_zf[M_TOT * DIM];

__device__ __forceinline__ ushort_t f2bf(float f) {  // RNE, finite inputs
    unsigned u = __float_as_uint(f);
    u += 0x7fffu + ((u >> 16) & 1u);
    return (ushort_t)(u >> 16);
}

__device__ __forceinline__ void gload_lds16(const ushort_t* g, ushort_t* l) {
    __builtin_amdgcn_global_load_lds(
        (const __attribute__((address_space(1))) void*)g,
        (__attribute__((address_space(3))) void*)l, 16, 0, 0);
}

// Stage one kk-slice (A 8KB + B 8KB) into one ring buffer.
// Wave w stages chunks {2w, 2w+1} of A and B: 4 gload_lds of 1KB per wave.
__device__ __forceinline__ void stage1(const ushort_t* gA, const ushort_t* gB,
                                       int kk, ushort_t* buf, int wave, int lane) {
#pragma unroll
    for (int i = 0; i < 2; ++i) {
        const int c = wave * 2 + i;
        gload_lds16(gA + (size_t)c * 4096 + kk * 512 + lane * 8, buf + c * 512);
        gload_lds16(gB + (size_t)c * 4096 + kk * 512 + lane * 8, buf + 4096 + c * 512);
    }
}

// ---------------- k_prep: convert(swizzled) + row norms + col sums -----------
// 512 blocks x 256 threads; wave w owns 4 rows; lane l owns cols [4l,4l+4).
__global__ __launch_bounds__(256) void k_prep(const float* __restrict__ X,
                                              const float* __restrict__ Y,
                                              float* __restrict__ sq,
                                              float* __restrict__ colsum_r,
                                              float* __restrict__ Ssum_r) {
    __shared__ float cpart[4][256];
    __shared__ float spart[4];
    const int t = threadIdx.x, wave = t >> 6, lane = t & 63;
    const int row0 = blockIdx.x * 16 + wave * 4;
    // swizzle coords for this lane's 4 columns [4l, 4l+4)
    const int kk = lane >> 3, q = (lane >> 1) & 3, j0 = (lane & 1) * 4;
    float c0 = 0.f, c1 = 0.f, c2 = 0.f, c3 = 0.f, ssum = 0.f;
#pragma unroll
    for (int i = 0; i < 4; ++i) {
        const int row = row0 + i;
        const float* p = (row < N_HALF) ? (X + (size_t)row * DIM)
                                        : (Y + (size_t)(row - N_HALF) * DIM);
        const float4 v = *((const float4*)p + lane);
        ushort4 hi;
        hi.x = f2bf(v.x); hi.y = f2bf(v.y); hi.z = f2bf(v.z); hi.w = f2bf(v.w);
        const int rb = row >> 4, m = row & 15;
        *(ushort4*)(g_zf + (size_t)rb * 4096 + kk * 512 + q * 128 + m * 8 + j0) = hi;
        c0 += v.x; c1 += v.y; c2 += v.z; c3 += v.w;
        float s = fmaf(v.x, v.x, fmaf(v.y, v.y, fmaf(v.z, v.z, v.w * v.w)));
#pragma unroll
        for (int off = 32; off > 0; off >>= 1) s += __shfl_xor(s, off);
        if (lane == 0) sq[row] = s;
        ssum += s;  // butterfly left full sum in every lane
    }
    float4 cp; cp.x = c0; cp.y = c1; cp.z = c2; cp.w = c3;
    *(float4*)&cpart[wave][lane * 4] = cp;
    if (lane == 0) spart[wave] = ssum;
    __syncthreads();
    const float cs = cpart[0][t] + cpart[1][t] + cpart[2][t] + cpart[3][t];
    const int rep = blockIdx.x & 7;  // 8 replicas -> 64 adds/address
    atomicAdd(&colsum_r[rep * 256 + t], cs);  // poison -3e-13/rep: harmless
    if (t == 0) atomicAdd(&Ssum_r[rep], spart[0] + spart[1] + spart[2] + spart[3]);
}

// ---------------- k_bw: one block computes exp2 scale c2 once ----------------
// Same summation order as the old per-block prologue -> bit-identical c2.
__global__ __launch_bounds__(256) void k_bw(const float* __restrict__ colsum_r,
                                            const float* __restrict__ Ssum_r,
                                            float* __restrict__ c2out) {
    __shared__ double sred[4];
    const int t = threadIdx.x, lane = t & 63, wave = t >> 6;
    float csf = 0.f;
#pragma unroll
    for (int r = 0; r < 8; ++r) csf += colsum_r[r * 256 + t];
    double p = (double)csf * (double)csf;
#pragma unroll
    for (int off = 32; off > 0; off >>= 1) p += __shfl_xor(p, off);
    if (lane == 0) sred[wave] = p;
    __syncthreads();
    if (t == 0) {
        const double SS = sred[0] + sred[1] + sred[2] + sred[3];
        float Sf = 0.f;
#pragma unroll
        for (int r = 0; r < 8; ++r) Sf += Ssum_r[r];
        const double sum_d2 = 2.0 * (double)M_TOT * (double)Sf - 2.0 * SS;
        const double bw = sum_d2 / ((double)M_TOT * (double)M_TOT - (double)M_TOT);
        c2out[0] = (float)(1.4426950408889634 / (4.0 * bw));  // exp2 scale
    }
}

// ---------------- k_gram: counted-vmcnt ring-pipelined MFMA Gram -------------
// 512 blocks x 256 threads = 2.0 blocks/CU; 4x16KB LDS ring, stage stream 3
// slices ahead of compute; vmcnt never drains to 0 in steady state.
__global__ __launch_bounds__(256, 2) void k_gram(const float* __restrict__ sq,
                                                 const float* __restrict__ c2p,
                                                 double* __restrict__ acc,
                                                 unsigned* __restrict__ cnt,
                                                 float* __restrict__ out) {
    // ring buf b: A slice [0,4096), B slice [4096,8192) ushorts (8 KB each).
    __shared__ __attribute__((aligned(16))) ushort_t lds[4][8192];
    __shared__ double redw[4][3];

    // XCD-band swizzle (512 = 8*64): same-XCD blocks contiguous in triangle.
    const int bid = (int)blockIdx.x;
    const int cc = (bid & 7) * 64 + (bid >> 3);
    // 32 long blocks (cc%16==0 -> 4 per XCD) do 5 tiles; rest do 4.
    const int nst = ((cc & 15) == 0) ? 5 : 4;
    const int f0 = cc * 4 + ((cc + 15) >> 4);  // first flat tile of this block

    const int t = threadIdx.x;
    const int lane = t & 63, wave = t >> 6;
    const int l15 = lane & 15, quad = lane >> 4;
    const int wrow = (wave >> 1) * 64, wcol = (wave & 1) * 64;
    const int a0 = (wave >> 1) * 4, b0 = (wave & 1) * 4;  // frag chunk bases
    const int laneoff = quad * 128 + l15 * 8;  // = lane*16B: linear, no conflict

    const float c2 = c2p[0];  // wave-uniform scalar load
    const float twoc2 = 2.f * c2;

    // triangular decode of f0 -> (ti, tj), tj >= ti
    int ti = (int)((129.0f - sqrtf(16641.0f - 8.0f * (float)f0)) * 0.5f);
    if (ti < 0) ti = 0; if (ti > NT - 1) ti = NT - 1;
    while (ti * NT - ti * (ti - 1) / 2 > f0) --ti;
    while ((ti + 1) * NT - (ti + 1) * ti / 2 <= f0) ++ti;
    int tj = ti + (f0 - (ti * NT - ti * (ti - 1) / 2));

    // stage stream (runs 3 slices ahead of compute)
    int s_ti = ti, s_tj = tj, s_kk = 0;
    const ushort_t* sgA = g_zf + (size_t)s_ti * 32768;
    const ushort_t* sgB = g_zf + (size_t)s_tj * 32768;
#define ADV_STAGE() do { if (++s_kk == 8) { s_kk = 0; ++s_tj;                 \
        if (s_tj == NT) { ++s_ti; s_tj = s_ti; }                              \
        sgA = g_zf + (size_t)s_ti * 32768;                                    \
        sgB = g_zf + (size_t)s_tj * 32768; } } while (0)

    // prime slices 0,1,2 into bufs 0,1,2 (12 loads in flight per wave)
#pragma unroll
    for (int p = 0; p < 3; ++p) {
        stage1(sgA, sgB, s_kk, lds[p], wave, lane);
        ADV_STAGE();
    }

    double lxx = 0.0, lxy = 0.0, lyy = 0.0;

#pragma unroll 1
    for (int s = 0; s < nst; ++s) {
        const bool last = (s == nst - 1);

        floatx4 accv[4][4];
#pragma unroll
        for (int mi = 0; mi < 4; ++mi)
#pragma unroll
            for (int ni = 0; ni < 4; ++ni) accv[mi][ni] = (floatx4)0.f;

#pragma unroll
        for (int kkc = 0; kkc < 8; ++kkc) {
            // counted wait: slice about to be read (4 loads) is complete once
            // <=8 outstanding (in-order retire; >=8 loads were issued after it,
            // counting the 2 in-flight slices and, post-epilogue, sq loads).
            if (last && kkc == 6)      asm volatile("s_waitcnt vmcnt(4)" ::: "memory");
            else if (last && kkc == 7) asm volatile("s_waitcnt vmcnt(0)" ::: "memory");
            else                       asm volatile("s_waitcnt vmcnt(8)" ::: "memory");
            __builtin_amdgcn_s_barrier();
            __builtin_amdgcn_sched_barrier(0);

            const ushort_t* lA = lds[kkc & 3];
            const ushort_t* lB = lds[kkc & 3] + 4096;
            short8 af[4], bf[4];
#pragma unroll
            for (int mi = 0; mi < 4; ++mi)
                af[mi] = *(const short8*)(lA + (a0 + mi) * 512 + laneoff);
#pragma unroll
            for (int ni = 0; ni < 4; ++ni)
                bf[ni] = *(const short8*)(lB + (b0 + ni) * 512 + laneoff);

            // issue stage of slice g+3 into buf (g+3)&3 (= buffer consumed at
            // phase g-1; all waves passed this phase's barrier after reading it)
            if (!last || kkc < 5) {
                stage1(sgA, sgB, s_kk, lds[(kkc + 3) & 3], wave, lane);
                ADV_STAGE();
            }

            __builtin_amdgcn_s_setprio(1);
#pragma unroll
            for (int mi = 0; mi < 4; ++mi)
#pragma unroll
                for (int ni = 0; ni < 4; ++ni)
                    accv[mi][ni] = __builtin_amdgcn_mfma_f32_16x16x32_bf16(
                        af[mi], bf[ni], accv[mi][ni], 0, 0, 0);
            __builtin_amdgcn_s_setprio(0);
        }

        // ---- epilogue for (ti, tj). C/D: col = lane&15, row = quad*4+reg.
        const int arow0 = ti * TILE, brow0 = tj * TILE;
        float nsj[4];
#pragma unroll
        for (int ni = 0; ni < 4; ++ni)
            nsj[ni] = -c2 * sq[brow0 + wcol + ni * 16 + l15];
        floatx4 nsi4[4];
#pragma unroll
        for (int mi = 0; mi < 4; ++mi) {
            const float4 sv = *(const float4*)&sq[arow0 + wrow + mi * 16 + quad * 4];
            nsi4[mi][0] = -c2 * sv.x; nsi4[mi][1] = -c2 * sv.y;
            nsi4[mi][2] = -c2 * sv.z; nsi4[mi][3] = -c2 * sv.w;
        }
        floatx4 sum4 = (floatx4)0.f;
#pragma unroll
        for (int mi = 0; mi < 4; ++mi) {
#pragma unroll
            for (int ni = 0; ni < 4; ++ni) {
                const floatx4 addv = nsi4[mi] + (floatx4)nsj[ni];
                floatx4 arg = twoc2 * accv[mi][ni] + addv;
                floatx4 tt;
#pragma unroll
                for (int r = 0; r < 4; ++r) tt[r] = exp2f(fminf(arg[r], 0.f));
                const floatx4 t2 = tt * tt, t4 = t2 * t2, t8 = t4 * t4, t16 = t8 * t8;
                sum4 += (tt + t2) + (t4 + t8) + t16;
            }
        }
        const float fsum = (sum4[0] + sum4[1]) + (sum4[2] + sum4[3]);
        const double contrib = ((ti == tj) ? 1.0 : 2.0) * (double)fsum;
        if (tj < NT_HALF)       lxx += contrib;   // block-uniform branches
        else if (ti < NT_HALF)  lxy += contrib;
        else                    lyy += contrib;

        // advance compute tile
        ++tj; if (tj == NT) { ++ti; tj = ti; }
    }
#undef ADV_STAGE

    // ---- block reduction + finalize ----
#pragma unroll
    for (int off = 32; off > 0; off >>= 1) {
        lxx += __shfl_xor(lxx, off);
        lxy += __shfl_xor(lxy, off);
        lyy += __shfl_xor(lyy, off);
    }
    if (lane == 0) { redw[wave][0] = lxx; redw[wave][1] = lxy; redw[wave][2] = lyy; }
    __syncthreads();
    if (t == 0) {
        double sxx = 0.0, sxy = 0.0, syy = 0.0;
#pragma unroll
        for (int wv = 0; wv < 4; ++wv) {
            sxx += redw[wv][0]; sxy += redw[wv][1]; syy += redw[wv][2];
        }
        if (sxx != 0.0) atomicAdd(&acc[0], sxx);
        if (sxy != 0.0) atomicAdd(&acc[1], sxy);
        if (syy != 0.0) atomicAdd(&acc[2], syy);
        __threadfence();  // release region adds before counter bump
        const unsigned old = atomicAdd(cnt, 1u);
        // counter starts at 0xAAAAAAAA (ws poison) or 0 — accept either
        if (old == (0xAAAAAAAAu + (unsigned)(NCHUNK - 1)) ||
            old == (unsigned)(NCHUNK - 1)) {
            const double xx = atomicAdd(&acc[0], 0.0);  // coherent reads
            const double xy = atomicAdd(&acc[1], 0.0);
            const double yy = atomicAdd(&acc[2], 0.0);
            out[0] = (float)((xx + yy - xy) *
                             (1.0 / ((double)N_HALF * (double)N_HALF)));
        }
    }
}

extern "C" void kernel_launch(void* const* d_in, const int* in_sizes, int n_in,
                              void* d_out, int out_size, void* d_ws, size_t ws_size,
                              hipStream_t stream) {
    const float* X = (const float*)d_in[0];
    const float* Y = (const float*)d_in[1];
    char* ws = (char*)d_ws;
    float* sq        = (float*)ws;               // 8192 f32  [0, 32768)
    float* colsum_r  = (float*)(ws + 32768);     // 8*256 f32 [32768, 40960)
    float* Ssum_r    = (float*)(ws + 40960);     // 8 f32     [40960, 40992)
    unsigned* cnt    = (unsigned*)(ws + 40992);  // 1 u32
    double* acc      = (double*)(ws + 41000);    // 3 f64 (8-aligned)
    float* c2ws      = (float*)(ws + 41024);     // 1 f32
    float* out = (float*)d_out;

    hipLaunchKernelGGL(k_prep, dim3(512), dim3(256), 0, stream,
                       X, Y, sq, colsum_r, Ssum_r);
    hipLaunchKernelGGL(k_bw, dim3(1), dim3(256), 0, stream,
                       colsum_r, Ssum_r, c2ws);
    hipLaunchKernelGGL(k_gram, dim3(NCHUNK), dim3(256), 0, stream,
                       sq, c2ws, acc, cnt, out);
}